// Round 1
// baseline (2294.932 us; speedup 1.0000x reference)
//
#include <hip/hip_runtime.h>
#include <hip/hip_bf16.h>

#define TOKS 32
#define EMB  64
#define NHEAD 4
#define HSZ  16
#define NLAYER 2
#define FFD  256
#define NVOC 65

// LDS row strides (padded to break bank conflicts)
#define XS 65
#define FS 257
#define AS 33

// LDS layout (floats)
#define SM_X   0
#define SM_H   2080
#define SM_Q   4160
#define SM_K   6240
#define SM_V   8320
#define SM_ATT 10400          // [4][32][33] = 4224
#define SM_FF  6240           // [32][257] = 8224, aliases K,V,ATT (dead by FF time)
#define SM_TOTAL 14624        // 58,496 bytes -> 2 blocks/CU

__device__ __forceinline__ void ln32(const float* __restrict__ src, float* __restrict__ dst,
                                     const float* __restrict__ g, const float* __restrict__ bta,
                                     int tid)
{
    const int row = tid >> 3;     // 32 rows
    const int j   = tid & 7;      // 8 threads per row
    const float* r = src + row * XS + j * 8;
    float v[8];
    float s = 0.f, s2 = 0.f;
#pragma unroll
    for (int i = 0; i < 8; ++i) {
        v[i] = r[i];
        s  += v[i];
        s2 += v[i] * v[i];
    }
#pragma unroll
    for (int m = 1; m <= 4; m <<= 1) {
        s  += __shfl_xor(s, m);
        s2 += __shfl_xor(s2, m);
    }
    const float mean = s * (1.f / 64.f);
    const float var  = s2 * (1.f / 64.f) - mean * mean;
    const float rstd = rsqrtf(var + 1e-5f);
    float* d = dst + row * XS + j * 8;
#pragma unroll
    for (int i = 0; i < 8; ++i)
        d[i] = (v[i] - mean) * rstd * g[j * 8 + i] + bta[j * 8 + i];
}

// out[32][64] = src[32][64] @ W[64][64]  (+bias) (+=dst)
template<bool ADD, bool BIAS>
__device__ __forceinline__ void mm64(const float* __restrict__ src, const float* __restrict__ W,
                                     const float* __restrict__ bias, float* __restrict__ dst, int tid)
{
    const int t0 = (tid >> 4) * 2;   // 2 rows per thread
    const int n0 = (tid & 15) * 4;   // 4 cols per thread
    float a0c[4] = {0.f, 0.f, 0.f, 0.f};
    float a1c[4] = {0.f, 0.f, 0.f, 0.f};
    const float* s0 = src + t0 * XS;
    const float* s1 = s0 + XS;
#pragma unroll 4
    for (int k = 0; k < 64; ++k) {
        const float a0 = s0[k];
        const float a1 = s1[k];
        const float4 w = *reinterpret_cast<const float4*>(W + k * 64 + n0);
        a0c[0] = fmaf(a0, w.x, a0c[0]); a0c[1] = fmaf(a0, w.y, a0c[1]);
        a0c[2] = fmaf(a0, w.z, a0c[2]); a0c[3] = fmaf(a0, w.w, a0c[3]);
        a1c[0] = fmaf(a1, w.x, a1c[0]); a1c[1] = fmaf(a1, w.y, a1c[1]);
        a1c[2] = fmaf(a1, w.z, a1c[2]); a1c[3] = fmaf(a1, w.w, a1c[3]);
    }
    float* d0 = dst + t0 * XS + n0;
    float* d1 = d0 + XS;
#pragma unroll
    for (int i = 0; i < 4; ++i) {
        float r0 = a0c[i], r1 = a1c[i];
        if (BIAS) { r0 += bias[n0 + i]; r1 += bias[n0 + i]; }
        if (ADD)  { d0[i] += r0; d1[i] += r1; }
        else      { d0[i] = r0;  d1[i] = r1; }
    }
}

__global__ __launch_bounds__(256, 2)
void gpt_fwd(const int* __restrict__ idx,
             const float* __restrict__ tok_emb,
             const float* __restrict__ pos_emb,
             const float* __restrict__ Wq_,
             const float* __restrict__ Wk_,
             const float* __restrict__ Wv_,
             const float* __restrict__ Wo_,
             const float* __restrict__ bo_,
             const float* __restrict__ g1_,
             const float* __restrict__ be1_,
             const float* __restrict__ g2_,
             const float* __restrict__ be2_,
             const float* __restrict__ W1_,
             const float* __restrict__ bf1_,
             const float* __restrict__ W2_,
             const float* __restrict__ bf2_,
             const float* __restrict__ gf,
             const float* __restrict__ bf,
             const float* __restrict__ Wh,
             const float* __restrict__ bh,
             float* __restrict__ out)
{
    __shared__ float smem[SM_TOTAL];
    const int tid = threadIdx.x;
    const int b = blockIdx.x;

    float* xb   = smem + SM_X;
    float* hb   = smem + SM_H;
    float* qb   = smem + SM_Q;
    float* kb   = smem + SM_K;
    float* vb   = smem + SM_V;
    float* attb = smem + SM_ATT;
    float* ffb  = smem + SM_FF;

    // ---- embedding: x[t][e] = tok_emb[idx[b][t]][e] + pos_emb[t][e]
    {
        const int* ib = idx + b * TOKS;
        for (int i = tid; i < TOKS * EMB; i += 256) {
            const int t = i >> 6, e = i & 63;
            xb[t * XS + e] = tok_emb[ib[t] * EMB + e] + pos_emb[i];
        }
    }
    __syncthreads();

    for (int l = 0; l < NLAYER; ++l) {
        const float* Wq = Wq_ + l * EMB * EMB;
        const float* Wk = Wk_ + l * EMB * EMB;
        const float* Wv = Wv_ + l * EMB * EMB;
        const float* Wo = Wo_ + l * EMB * EMB;
        const float* bo = bo_ + l * EMB;
        const float* W1 = W1_ + l * EMB * FFD;
        const float* b1 = bf1_ + l * FFD;
        const float* W2 = W2_ + l * FFD * EMB;
        const float* b2 = bf2_ + l * EMB;

        // ---- LN1
        ln32(xb, hb, g1_ + l * EMB, be1_ + l * EMB, tid);
        __syncthreads();

        // ---- QKV projections
        mm64<false, false>(hb, Wq, nullptr, qb, tid);
        mm64<false, false>(hb, Wk, nullptr, kb, tid);
        mm64<false, false>(hb, Wv, nullptr, vb, tid);
        __syncthreads();

        // ---- attention: wave = head, 2 lanes per query row
        {
            const int h    = tid >> 6;
            const int lane = tid & 63;
            const int t    = lane >> 1;
            const int j    = lane & 1;
            float* arow = attb + h * (TOKS * AS) + t * AS;

            float qreg[HSZ];
            const float* qrow = qb + t * XS + h * HSZ;
#pragma unroll
            for (int d = 0; d < HSZ; ++d) qreg[d] = qrow[d];

            float mx = -1e30f;
            for (int s = j; s <= t; s += 2) {
                const float* krow = kb + s * XS + h * HSZ;
                float acc = 0.f;
#pragma unroll
                for (int d = 0; d < HSZ; ++d) acc = fmaf(qreg[d], krow[d], acc);
                acc *= 0.125f;               // scale = E^-0.5 = 1/8
                arow[s] = acc;
                mx = fmaxf(mx, acc);
            }
            mx = fmaxf(mx, __shfl_xor(mx, 1));
            float sum = 0.f;
            for (int s = j; s <= t; s += 2) {
                const float e = __expf(arow[s] - mx);
                arow[s] = e;
                sum += e;
            }
            sum += __shfl_xor(sum, 1);
            const float inv = 1.f / sum;
            __syncthreads();                  // make all att rows + exp values visible

            // PV: o[t][h*16 + j*8 .. +8)
            float o[8] = {0.f, 0.f, 0.f, 0.f, 0.f, 0.f, 0.f, 0.f};
            const int d0 = h * HSZ + j * 8;
            for (int s = 0; s <= t; ++s) {
                const float a = arow[s];
                const float* vrow = vb + s * XS + d0;
#pragma unroll
                for (int d = 0; d < 8; ++d) o[d] = fmaf(a, vrow[d], o[d]);
            }
            float* orow = hb + t * XS + d0;   // o overwrites h (dead)
#pragma unroll
            for (int d = 0; d < 8; ++d) orow[d] = o[d] * inv;
        }
        __syncthreads();

        // ---- x += o @ Wo + bo
        mm64<true, true>(hb, Wo, bo, xb, tid);
        __syncthreads();

        // ---- LN2 -> qb (reuse)
        ln32(xb, qb, g2_ + l * EMB, be2_ + l * EMB, tid);
        __syncthreads();

        // ---- FF1: ff = relu(h2 @ W1 + b1)   [32][256]
        {
            const int t0 = (tid >> 4) * 2;
            const int n0 = (tid & 15) * 16;
            float acc0[16], acc1[16];
#pragma unroll
            for (int i = 0; i < 16; ++i) { acc0[i] = 0.f; acc1[i] = 0.f; }
            const float* s0 = qb + t0 * XS;
            const float* s1 = s0 + XS;
#pragma unroll 2
            for (int k = 0; k < 64; ++k) {
                const float a0 = s0[k];
                const float a1 = s1[k];
#pragma unroll
                for (int q4 = 0; q4 < 4; ++q4) {
                    const float4 w = *reinterpret_cast<const float4*>(W1 + k * FFD + n0 + q4 * 4);
                    acc0[q4*4+0] = fmaf(a0, w.x, acc0[q4*4+0]);
                    acc0[q4*4+1] = fmaf(a0, w.y, acc0[q4*4+1]);
                    acc0[q4*4+2] = fmaf(a0, w.z, acc0[q4*4+2]);
                    acc0[q4*4+3] = fmaf(a0, w.w, acc0[q4*4+3]);
                    acc1[q4*4+0] = fmaf(a1, w.x, acc1[q4*4+0]);
                    acc1[q4*4+1] = fmaf(a1, w.y, acc1[q4*4+1]);
                    acc1[q4*4+2] = fmaf(a1, w.z, acc1[q4*4+2]);
                    acc1[q4*4+3] = fmaf(a1, w.w, acc1[q4*4+3]);
                }
            }
            float* d0 = ffb + t0 * FS + n0;
            float* d1 = d0 + FS;
#pragma unroll
            for (int i = 0; i < 16; ++i) {
                const float bb = b1[n0 + i];
                d0[i] = fmaxf(acc0[i] + bb, 0.f);
                d1[i] = fmaxf(acc1[i] + bb, 0.f);
            }
        }
        __syncthreads();

        // ---- FF2: x += ff @ W2 + b2
        {
            const int t0 = (tid >> 4) * 2;
            const int n0 = (tid & 15) * 4;
            float acc0[4] = {0.f,0.f,0.f,0.f}, acc1[4] = {0.f,0.f,0.f,0.f};
            const float* s0 = ffb + t0 * FS;
            const float* s1 = s0 + FS;
#pragma unroll 4
            for (int k = 0; k < FFD; ++k) {
                const float a0 = s0[k];
                const float a1 = s1[k];
                const float4 w = *reinterpret_cast<const float4*>(W2 + k * EMB + n0);
                acc0[0] = fmaf(a0, w.x, acc0[0]); acc0[1] = fmaf(a0, w.y, acc0[1]);
                acc0[2] = fmaf(a0, w.z, acc0[2]); acc0[3] = fmaf(a0, w.w, acc0[3]);
                acc1[0] = fmaf(a1, w.x, acc1[0]); acc1[1] = fmaf(a1, w.y, acc1[1]);
                acc1[2] = fmaf(a1, w.z, acc1[2]); acc1[3] = fmaf(a1, w.w, acc1[3]);
            }
            float* d0 = xb + t0 * XS + n0;
            float* d1 = d0 + XS;
#pragma unroll
            for (int i = 0; i < 4; ++i) {
                const float bb = b2[n0 + i];
                d0[i] += acc0[i] + bb;
                d1[i] += acc1[i] + bb;
            }
        }
        __syncthreads();
    }

    // ---- final LN + head
    ln32(xb, hb, gf, bf, tid);
    __syncthreads();

    const size_t obase = (size_t)b * TOKS * NVOC;
    for (int i = tid; i < TOKS * NVOC; i += 256) {
        const int t = i / NVOC;
        const int n = i - t * NVOC;
        float acc = bh[n];
        const float* hr = hb + t * XS;
#pragma unroll 8
        for (int k = 0; k < EMB; ++k) acc = fmaf(hr[k], Wh[k * NVOC + n], acc);
        out[obase + i] = acc;
    }
}

extern "C" void kernel_launch(void* const* d_in, const int* in_sizes, int n_in,
                              void* d_out, int out_size, void* d_ws, size_t ws_size,
                              hipStream_t stream) {
    (void)n_in; (void)d_ws; (void)ws_size; (void)out_size;
    const int*   idx     = (const int*)d_in[0];
    const float* tok_emb = (const float*)d_in[1];
    const float* pos_emb = (const float*)d_in[2];
    const float* Wq      = (const float*)d_in[3];
    const float* Wk      = (const float*)d_in[4];
    const float* Wv      = (const float*)d_in[5];
    const float* Wo      = (const float*)d_in[6];
    const float* bo      = (const float*)d_in[7];
    const float* ln1_g   = (const float*)d_in[8];
    const float* ln1_b   = (const float*)d_in[9];
    const float* ln2_g   = (const float*)d_in[10];
    const float* ln2_b   = (const float*)d_in[11];
    const float* W1      = (const float*)d_in[12];
    const float* b1      = (const float*)d_in[13];
    const float* W2      = (const float*)d_in[14];
    const float* b2      = (const float*)d_in[15];
    const float* lnf_g   = (const float*)d_in[16];
    const float* lnf_b   = (const float*)d_in[17];
    const float* Wh      = (const float*)d_in[18];
    const float* bh      = (const float*)d_in[19];
    float* out = (float*)d_out;

    const int nblocks = in_sizes[0] / TOKS;   // B = 8192
    gpt_fwd<<<dim3(nblocks), dim3(256), 0, stream>>>(
        idx, tok_emb, pos_emb, Wq, Wk, Wv, Wo, bo,
        ln1_g, ln1_b, ln2_g, ln2_b, W1, b1, W2, b2,
        lnf_g, lnf_b, Wh, bh, out);
}